// Round 5
// baseline (1089.106 us; speedup 1.0000x reference)
//
#include <hip/hip_runtime.h>

#define TSTEPS 100
#define BC     32
#define NBLK   (16384/BC)   // 512 blocks

typedef __attribute__((ext_vector_type(8))) short bf16x8;
typedef __attribute__((ext_vector_type(4))) float f32x4;

// d_ws layout: ushort view for bf16 frags, float view for biases
#define WS_WHH0_U 0         // 16384 ushort
#define WS_WIH1_U 16384
#define WS_WHH1_U 32768
#define WS_WIH0_U 49152     // 8192 ushort -> ends at byte 114688
#define WS_B0_F   28672     // float idx (byte 114688)
#define WS_B1_F   28928

#define MFMA(A,B,C) __builtin_amdgcn_mfma_f32_16x16x32_bf16(A,B,C,0,0,0)
#define LOG2E 1.4426950408889634f

// RNE (one-shot weight formatting only)
__device__ __forceinline__ unsigned short f2bf_rne(float f) {
    unsigned int u = __float_as_uint(f);
    u += 0x7fffu + ((u >> 16) & 1u);
    return (unsigned short)(u >> 16);
}
// hot-loop: round-nearest-ties-up, 2 VALU ops
__device__ __forceinline__ unsigned short f2bf(float f) {
    return (unsigned short)((__float_as_uint(f) + 0x8000u) >> 16);
}
__device__ __forceinline__ float fsig(float x) {
    return __builtin_amdgcn_rcpf(1.0f + __builtin_amdgcn_exp2f(-LOG2E * x));
}
__device__ __forceinline__ float ftanh(float x) {
    const float e = __builtin_amdgcn_exp2f((2.0f * LOG2E) * x);
    return fmaf(-2.0f, __builtin_amdgcn_rcpf(e + 1.0f), 1.0f);
}

// One-shot: format weights into per-lane MFMA B-fragment order (bf16) + fused biases.
// Frag (ug,G,kc): lane l, elem j  <->  W[row = G*64 + ug*16 + (l&15)][k = kc*32 + (l>>4)*8 + j]
__global__ void reorder_w(const float* __restrict__ Wih0, const float* __restrict__ Whh0,
                          const float* __restrict__ bih0, const float* __restrict__ bhh0,
                          const float* __restrict__ Wih1, const float* __restrict__ Whh1,
                          const float* __restrict__ bih1, const float* __restrict__ bhh1,
                          unsigned short* __restrict__ wsu, float* __restrict__ wsf)
{
    const int idx = blockIdx.x * 256 + threadIdx.x;   // 0..24575
    if (idx < 16384) {
        const int j = idx & 7, lane = (idx >> 3) & 63, kc = (idx >> 9) & 1,
                  G = (idx >> 10) & 3, ug = (idx >> 12) & 3;
        const int row = G * 64 + ug * 16 + (lane & 15);
        const int k   = kc * 32 + (lane >> 4) * 8 + j;
        wsu[WS_WHH0_U + idx] = f2bf_rne(Whh0[row * 64 + k]);
        wsu[WS_WIH1_U + idx] = f2bf_rne(Wih1[row * 64 + k]);
        wsu[WS_WHH1_U + idx] = f2bf_rne(Whh1[row * 64 + k]);
    }
    if (idx < 8192) {
        const int j = idx & 7, lane = (idx >> 3) & 63, G = (idx >> 9) & 3, ug = (idx >> 11) & 3;
        const int row = G * 64 + ug * 16 + (lane & 15);
        const float v = ((lane >> 4) == 0 && j < 4) ? Wih0[row * 4 + j] : 0.0f;
        wsu[WS_WIH0_U + idx] = f2bf_rne(v);
    }
    if (idx < 256) {
        wsf[WS_B0_F + idx] = bih0[idx] + bhh0[idx];
        wsf[WS_B1_F + idx] = bih1[idx] + bhh1[idx];
    }
}

__global__ __launch_bounds__(512, 4) void lstm2_mfma(
    const float* __restrict__ x,
    const unsigned short* __restrict__ wsu, const float* __restrict__ wsf,
    const float* __restrict__ gam, const float* __restrict__ bet,
    const float* __restrict__ Wfc, const float* __restrict__ bfc,
    float* __restrict__ out)
{
    // h as bf16 [batch][unit], pitch 72 ushort (144B rows, b128-aligned frag reads)
    // XOR-swizzle bit5 by (row_local>>3) on BOTH write & read -> conflict-free writes
    __shared__ __align__(16) unsigned short H0[BC * 72];
    __shared__ __align__(16) unsigned short H1[BC * 72];
    __shared__ float H1F[BC * 65];   // f32 h1 for the LayerNorm epilogue (last step only)

    const int tid  = threadIdx.x;
    const int lane = tid & 63;
    const int wv   = __builtin_amdgcn_readfirstlane(tid >> 6); // 0..7
    const int mt = wv >> 2, ug = wv & 3;      // batch-tile, unit-group
    const int ln15 = lane & 15, lg = lane >> 4;
    const int bblk = blockIdx.x * BC;

    // ---- load resident weight B-fragments (one-time) ----
    bf16x8 Bhh0[4][2], Bih1[4][2], Bhh1[4][2], Bih0[4];
    #pragma unroll
    for (int G = 0; G < 4; ++G) {
        #pragma unroll
        for (int kc = 0; kc < 2; ++kc) {
            const int f = ((ug * 4 + G) * 2 + kc) * 512 + lane * 8;
            Bhh0[G][kc] = *(const bf16x8*)(wsu + WS_WHH0_U + f);
            Bih1[G][kc] = *(const bf16x8*)(wsu + WS_WIH1_U + f);
            Bhh1[G][kc] = *(const bf16x8*)(wsu + WS_WHH1_U + f);
        }
        Bih0[G] = *(const bf16x8*)(wsu + WS_WIH0_U + (ug * 4 + G) * 512 + lane * 8);
    }
    // biases as persistent broadcast fragments (C-operand of first MFMA per tile)
    f32x4 b0v[4], b1v[4];
    #pragma unroll
    for (int G = 0; G < 4; ++G) {
        const float b0 = wsf[WS_B0_F + G * 64 + ug * 16 + ln15];
        const float b1 = wsf[WS_B1_F + G * 64 + ug * 16 + ln15];
        b0v[G] = (f32x4){b0, b0, b0, b0};
        b1v[G] = (f32x4){b1, b1, b1, b1};
    }

    // ---- hoisted LDS byte addresses (t-invariant) ----
    const unsigned wswz = (unsigned)(((lg >> 1) & 1) << 5);
    unsigned wo[4];
    #pragma unroll
    for (int r = 0; r < 4; ++r)
        wo[r] = ((unsigned)(((mt * 16 + lg * 4 + r) * 72 + ug * 16 + ln15) * 2)) ^ wswz;
    const unsigned rswz = (unsigned)(((ln15 >> 3) & 1) << 5);
    const unsigned ro = ((unsigned)((mt * 16 + ln15) * 144 + lg * 16)) ^ rswz;  // kc=0; kc=1 at +64
    char* const H0c = (char*)H0;
    char* const H1c = (char*)H1;

    float c0[4] = {0.f,0.f,0.f,0.f}, c1[4] = {0.f,0.f,0.f,0.f};
    const bf16x8 zfrag = {0,0,0,0,0,0,0,0};
    bf16x8 A0[2], A1[2];
    A0[0] = zfrag; A0[1] = zfrag; A1[0] = zfrag; A1[1] = zfrag;   // h(-1) = 0

    const float* xb = x + (size_t)(bblk + mt * 16 + ln15) * (TSTEPS * 4);
    float4 xf = *(const float4*)(xb);   // x_0

    for (int t = 0; t < TSTEPS; ++t) {
        // ---------- layer 0 ----------
        bf16x8 ax = zfrag;
        if (lg == 0) {
            ax[0] = (short)f2bf_rne(xf.x); ax[1] = (short)f2bf_rne(xf.y);
            ax[2] = (short)f2bf_rne(xf.z); ax[3] = (short)f2bf_rne(xf.w);
        }
        f32x4 acc[4];
        #pragma unroll
        for (int G = 0; G < 4; ++G) {
            acc[G] = MFMA(A0[0], Bhh0[G][0], b0v[G]);
            acc[G] = MFMA(A0[1], Bhh0[G][1], acc[G]);
            acc[G] = MFMA(ax,    Bih0[G],    acc[G]);
        }
        if (t + 1 < TSTEPS) xf = *(const float4*)(xb + (t + 1) * 4);  // prefetch

        #pragma unroll
        for (int r = 0; r < 4; ++r) {
            const float ig = fsig(acc[0][r]), fg = fsig(acc[1][r]);
            const float gg = ftanh(acc[2][r]), og = fsig(acc[3][r]);
            const float c = fg * c0[r] + ig * gg; c0[r] = c;
            *(unsigned short*)(H0c + wo[r]) = f2bf(og * ftanh(c));
        }
        __syncthreads();
        A0[0] = *(const bf16x8*)(H0c + ro);
        A0[1] = *(const bf16x8*)(H0c + ro + 64);

        // ---------- layer 1 ----------
        #pragma unroll
        for (int G = 0; G < 4; ++G) {
            acc[G] = MFMA(A0[0], Bih1[G][0], b1v[G]);
            acc[G] = MFMA(A0[1], Bih1[G][1], acc[G]);
            acc[G] = MFMA(A1[0], Bhh1[G][0], acc[G]);
            acc[G] = MFMA(A1[1], Bhh1[G][1], acc[G]);
        }
        #pragma unroll
        for (int r = 0; r < 4; ++r) {
            const float ig = fsig(acc[0][r]), fg = fsig(acc[1][r]);
            const float gg = ftanh(acc[2][r]), og = fsig(acc[3][r]);
            const float c = fg * c1[r] + ig * gg; c1[r] = c;
            const float h = og * ftanh(c);
            *(unsigned short*)(H1c + wo[r]) = f2bf(h);
            if (t == TSTEPS - 1)
                H1F[(mt * 16 + lg * 4 + r) * 65 + ug * 16 + ln15] = h;
        }
        __syncthreads();
        A1[0] = *(const bf16x8*)(H1c + ro);
        A1[1] = *(const bf16x8*)(H1c + ro + 64);
    }

    // ---------- LayerNorm + FC on h1(T-1), f32 path ----------
    if (tid < BC) {
        const int b = tid;
        float hr[64];
        float mu = 0.f;
        #pragma unroll
        for (int k = 0; k < 64; ++k) { hr[k] = H1F[b * 65 + k]; mu += hr[k]; }
        mu *= (1.f / 64.f);
        float var = 0.f;
        #pragma unroll
        for (int k = 0; k < 64; ++k) { const float d = hr[k] - mu; var = fmaf(d, d, var); }
        var *= (1.f / 64.f);
        const float rs = rsqrtf(var + 1e-5f);
        float o0 = bfc[0], o1 = bfc[1];
        #pragma unroll
        for (int k = 0; k < 64; ++k) {
            const float nk = (hr[k] - mu) * rs * gam[k] + bet[k];
            o0 = fmaf(nk, Wfc[k],      o0);
            o1 = fmaf(nk, Wfc[64 + k], o1);
        }
        out[(size_t)(bblk + b) * 2 + 0] = o0;
        out[(size_t)(bblk + b) * 2 + 1] = o1;
    }
}

extern "C" void kernel_launch(void* const* d_in, const int* in_sizes, int n_in,
                              void* d_out, int out_size, void* d_ws, size_t ws_size,
                              hipStream_t stream) {
    (void)in_sizes; (void)n_in; (void)out_size; (void)ws_size;
    const float* x    = (const float*)d_in[0];
    const float* Wih0 = (const float*)d_in[1];
    const float* Whh0 = (const float*)d_in[2];
    const float* bih0 = (const float*)d_in[3];
    const float* bhh0 = (const float*)d_in[4];
    const float* Wih1 = (const float*)d_in[5];
    const float* Whh1 = (const float*)d_in[6];
    const float* bih1 = (const float*)d_in[7];
    const float* bhh1 = (const float*)d_in[8];
    const float* gam  = (const float*)d_in[9];
    const float* bet  = (const float*)d_in[10];
    const float* Wfc  = (const float*)d_in[11];
    const float* bfc  = (const float*)d_in[12];
    unsigned short* wsu = (unsigned short*)d_ws;
    float*          wsf = (float*)d_ws;
    float* out = (float*)d_out;

    hipLaunchKernelGGL(reorder_w, dim3(96), dim3(256), 0, stream,
                       Wih0, Whh0, bih0, bhh0, Wih1, Whh1, bih1, bhh1, wsu, wsf);
    hipLaunchKernelGGL(lstm2_mfma, dim3(NBLK), dim3(512), 0, stream,
                       x, wsu, wsf, gam, bet, Wfc, bfc, out);
}

// Round 6
// 317.440 us; speedup vs baseline: 3.4309x; 3.4309x over previous
//
#include <hip/hip_runtime.h>

#define TSTEPS 100
#define BC     32
#define NBLK   (16384/BC)   // 512 blocks

typedef __attribute__((ext_vector_type(8))) short bf16x8;
typedef __attribute__((ext_vector_type(4))) float f32x4;

// d_ws layout: ushort view for bf16 frags, float view for biases
#define WS_WHH0_U 0         // 16384 ushort
#define WS_WIH1_U 16384
#define WS_WHH1_U 32768
#define WS_WIH0_U 49152     // 8192 ushort -> ends at byte 114688
#define WS_B0_F   28672     // float idx (byte 114688)
#define WS_B1_F   28928

#define MFMA(A,B,C) __builtin_amdgcn_mfma_f32_16x16x32_bf16(A,B,C,0,0,0)
#define LOG2E 1.4426950408889634f

// RNE (one-shot weight formatting only)
__device__ __forceinline__ unsigned short f2bf_rne(float f) {
    unsigned int u = __float_as_uint(f);
    u += 0x7fffu + ((u >> 16) & 1u);
    return (unsigned short)(u >> 16);
}
// hot-loop: round-nearest-ties-up, 2 VALU ops
__device__ __forceinline__ unsigned short f2bf(float f) {
    return (unsigned short)((__float_as_uint(f) + 0x8000u) >> 16);
}
__device__ __forceinline__ float fsig(float x) {
    return __builtin_amdgcn_rcpf(1.0f + __builtin_amdgcn_exp2f(-LOG2E * x));
}
__device__ __forceinline__ float ftanh(float x) {
    const float e = __builtin_amdgcn_exp2f((2.0f * LOG2E) * x);
    return fmaf(-2.0f, __builtin_amdgcn_rcpf(e + 1.0f), 1.0f);
}

// One-shot: format weights into per-lane MFMA B-fragment order (bf16) + fused biases.
// Frag (ug,G,kc): lane l, elem j  <->  W[row = G*64 + ug*16 + (l&15)][k = kc*32 + (l>>4)*8 + j]
__global__ void reorder_w(const float* __restrict__ Wih0, const float* __restrict__ Whh0,
                          const float* __restrict__ bih0, const float* __restrict__ bhh0,
                          const float* __restrict__ Wih1, const float* __restrict__ Whh1,
                          const float* __restrict__ bih1, const float* __restrict__ bhh1,
                          unsigned short* __restrict__ wsu, float* __restrict__ wsf)
{
    const int idx = blockIdx.x * 256 + threadIdx.x;   // 0..24575
    if (idx < 16384) {
        const int j = idx & 7, lane = (idx >> 3) & 63, kc = (idx >> 9) & 1,
                  G = (idx >> 10) & 3, ug = (idx >> 12) & 3;
        const int row = G * 64 + ug * 16 + (lane & 15);
        const int k   = kc * 32 + (lane >> 4) * 8 + j;
        wsu[WS_WHH0_U + idx] = f2bf_rne(Whh0[row * 64 + k]);
        wsu[WS_WIH1_U + idx] = f2bf_rne(Wih1[row * 64 + k]);
        wsu[WS_WHH1_U + idx] = f2bf_rne(Whh1[row * 64 + k]);
    }
    if (idx < 8192) {
        const int j = idx & 7, lane = (idx >> 3) & 63, G = (idx >> 9) & 3, ug = (idx >> 11) & 3;
        const int row = G * 64 + ug * 16 + (lane & 15);
        const float v = ((lane >> 4) == 0 && j < 4) ? Wih0[row * 4 + j] : 0.0f;
        wsu[WS_WIH0_U + idx] = f2bf_rne(v);
    }
    if (idx < 256) {
        wsf[WS_B0_F + idx] = bih0[idx] + bhh0[idx];
        wsf[WS_B1_F + idx] = bih1[idx] + bhh1[idx];
    }
}

// launch_bounds (512,2): round-4-verified no-spill point (VGPR=104).
// (512,4) caps VGPR at 64 -> 112 regs of resident weight frags spill to
// scratch -> 4 GB/dispatch HBM traffic (round-5 regression).
__global__ __launch_bounds__(512, 2) void lstm2_mfma(
    const float* __restrict__ x,
    const unsigned short* __restrict__ wsu, const float* __restrict__ wsf,
    const float* __restrict__ gam, const float* __restrict__ bet,
    const float* __restrict__ Wfc, const float* __restrict__ bfc,
    float* __restrict__ out)
{
    // h as bf16 [batch][unit], pitch 72 ushort (144B rows, b128-aligned frag reads)
    // XOR-swizzle bit5 by (row_local>>3) on BOTH write & read -> conflict-free writes
    __shared__ __align__(16) unsigned short H0[BC * 72];
    __shared__ __align__(16) unsigned short H1[BC * 72];
    __shared__ float H1F[BC * 65];   // f32 h1 for the LayerNorm epilogue (last step only)

    const int tid  = threadIdx.x;
    const int lane = tid & 63;
    const int wv   = __builtin_amdgcn_readfirstlane(tid >> 6); // 0..7
    const int mt = wv >> 2, ug = wv & 3;      // batch-tile, unit-group
    const int ln15 = lane & 15, lg = lane >> 4;
    const int bblk = blockIdx.x * BC;

    // ---- load resident weight B-fragments (one-time) ----
    bf16x8 Bhh0[4][2], Bih1[4][2], Bhh1[4][2], Bih0[4];
    #pragma unroll
    for (int G = 0; G < 4; ++G) {
        #pragma unroll
        for (int kc = 0; kc < 2; ++kc) {
            const int f = ((ug * 4 + G) * 2 + kc) * 512 + lane * 8;
            Bhh0[G][kc] = *(const bf16x8*)(wsu + WS_WHH0_U + f);
            Bih1[G][kc] = *(const bf16x8*)(wsu + WS_WIH1_U + f);
            Bhh1[G][kc] = *(const bf16x8*)(wsu + WS_WHH1_U + f);
        }
        Bih0[G] = *(const bf16x8*)(wsu + WS_WIH0_U + (ug * 4 + G) * 512 + lane * 8);
    }
    // biases as persistent broadcast fragments (C-operand of first MFMA per tile)
    f32x4 b0v[4], b1v[4];
    #pragma unroll
    for (int G = 0; G < 4; ++G) {
        const float b0 = wsf[WS_B0_F + G * 64 + ug * 16 + ln15];
        const float b1 = wsf[WS_B1_F + G * 64 + ug * 16 + ln15];
        b0v[G] = (f32x4){b0, b0, b0, b0};
        b1v[G] = (f32x4){b1, b1, b1, b1};
    }

    // ---- hoisted LDS byte addresses (t-invariant) ----
    const unsigned wswz = (unsigned)(((lg >> 1) & 1) << 5);
    unsigned wo[4];
    #pragma unroll
    for (int r = 0; r < 4; ++r)
        wo[r] = ((unsigned)(((mt * 16 + lg * 4 + r) * 72 + ug * 16 + ln15) * 2)) ^ wswz;
    const unsigned rswz = (unsigned)(((ln15 >> 3) & 1) << 5);
    const unsigned ro = ((unsigned)((mt * 16 + ln15) * 144 + lg * 16)) ^ rswz;  // kc=0; kc=1 at +64
    char* const H0c = (char*)H0;
    char* const H1c = (char*)H1;

    float c0[4] = {0.f,0.f,0.f,0.f}, c1[4] = {0.f,0.f,0.f,0.f};
    const bf16x8 zfrag = {0,0,0,0,0,0,0,0};
    bf16x8 A0[2], A1[2];
    A0[0] = zfrag; A0[1] = zfrag; A1[0] = zfrag; A1[1] = zfrag;   // h(-1) = 0

    const float* xb = x + (size_t)(bblk + mt * 16 + ln15) * (TSTEPS * 4);
    float4 xf = *(const float4*)(xb);   // x_0

    for (int t = 0; t < TSTEPS; ++t) {
        // ---------- layer 0 ----------
        bf16x8 ax = zfrag;
        if (lg == 0) {
            ax[0] = (short)f2bf_rne(xf.x); ax[1] = (short)f2bf_rne(xf.y);
            ax[2] = (short)f2bf_rne(xf.z); ax[3] = (short)f2bf_rne(xf.w);
        }
        f32x4 acc[4];
        #pragma unroll
        for (int G = 0; G < 4; ++G) {
            acc[G] = MFMA(A0[0], Bhh0[G][0], b0v[G]);
            acc[G] = MFMA(A0[1], Bhh0[G][1], acc[G]);
            acc[G] = MFMA(ax,    Bih0[G],    acc[G]);
        }
        if (t + 1 < TSTEPS) xf = *(const float4*)(xb + (t + 1) * 4);  // prefetch

        #pragma unroll
        for (int r = 0; r < 4; ++r) {
            const float ig = fsig(acc[0][r]), fg = fsig(acc[1][r]);
            const float gg = ftanh(acc[2][r]), og = fsig(acc[3][r]);
            const float c = fg * c0[r] + ig * gg; c0[r] = c;
            *(unsigned short*)(H0c + wo[r]) = f2bf(og * ftanh(c));
        }
        __syncthreads();
        A0[0] = *(const bf16x8*)(H0c + ro);
        A0[1] = *(const bf16x8*)(H0c + ro + 64);

        // ---------- layer 1 ----------
        #pragma unroll
        for (int G = 0; G < 4; ++G) {
            acc[G] = MFMA(A0[0], Bih1[G][0], b1v[G]);
            acc[G] = MFMA(A0[1], Bih1[G][1], acc[G]);
            acc[G] = MFMA(A1[0], Bhh1[G][0], acc[G]);
            acc[G] = MFMA(A1[1], Bhh1[G][1], acc[G]);
        }
        #pragma unroll
        for (int r = 0; r < 4; ++r) {
            const float ig = fsig(acc[0][r]), fg = fsig(acc[1][r]);
            const float gg = ftanh(acc[2][r]), og = fsig(acc[3][r]);
            const float c = fg * c1[r] + ig * gg; c1[r] = c;
            const float h = og * ftanh(c);
            *(unsigned short*)(H1c + wo[r]) = f2bf(h);
            if (t == TSTEPS - 1)
                H1F[(mt * 16 + lg * 4 + r) * 65 + ug * 16 + ln15] = h;
        }
        __syncthreads();
        A1[0] = *(const bf16x8*)(H1c + ro);
        A1[1] = *(const bf16x8*)(H1c + ro + 64);
    }

    // ---------- LayerNorm + FC on h1(T-1), f32 path ----------
    if (tid < BC) {
        const int b = tid;
        float hr[64];
        float mu = 0.f;
        #pragma unroll
        for (int k = 0; k < 64; ++k) { hr[k] = H1F[b * 65 + k]; mu += hr[k]; }
        mu *= (1.f / 64.f);
        float var = 0.f;
        #pragma unroll
        for (int k = 0; k < 64; ++k) { const float d = hr[k] - mu; var = fmaf(d, d, var); }
        var *= (1.f / 64.f);
        const float rs = rsqrtf(var + 1e-5f);
        float o0 = bfc[0], o1 = bfc[1];
        #pragma unroll
        for (int k = 0; k < 64; ++k) {
            const float nk = (hr[k] - mu) * rs * gam[k] + bet[k];
            o0 = fmaf(nk, Wfc[k],      o0);
            o1 = fmaf(nk, Wfc[64 + k], o1);
        }
        out[(size_t)(bblk + b) * 2 + 0] = o0;
        out[(size_t)(bblk + b) * 2 + 1] = o1;
    }
}

extern "C" void kernel_launch(void* const* d_in, const int* in_sizes, int n_in,
                              void* d_out, int out_size, void* d_ws, size_t ws_size,
                              hipStream_t stream) {
    (void)in_sizes; (void)n_in; (void)out_size; (void)ws_size;
    const float* x    = (const float*)d_in[0];
    const float* Wih0 = (const float*)d_in[1];
    const float* Whh0 = (const float*)d_in[2];
    const float* bih0 = (const float*)d_in[3];
    const float* bhh0 = (const float*)d_in[4];
    const float* Wih1 = (const float*)d_in[5];
    const float* Whh1 = (const float*)d_in[6];
    const float* bih1 = (const float*)d_in[7];
    const float* bhh1 = (const float*)d_in[8];
    const float* gam  = (const float*)d_in[9];
    const float* bet  = (const float*)d_in[10];
    const float* Wfc  = (const float*)d_in[11];
    const float* bfc  = (const float*)d_in[12];
    unsigned short* wsu = (unsigned short*)d_ws;
    float*          wsf = (float*)d_ws;
    float* out = (float*)d_out;

    hipLaunchKernelGGL(reorder_w, dim3(96), dim3(256), 0, stream,
                       Wih0, Whh0, bih0, bhh0, Wih1, Whh1, bih1, bhh1, wsu, wsf);
    hipLaunchKernelGGL(lstm2_mfma, dim3(NBLK), dim3(512), 0, stream,
                       x, wsu, wsf, gam, bet, Wfc, bfc, out);
}

// Round 7
// 295.365 us; speedup vs baseline: 3.6873x; 1.0747x over previous
//
#include <hip/hip_runtime.h>

#define TSTEPS 100
#define BC     16
#define NBLK   (16384/BC)   // 1024 blocks

typedef __attribute__((ext_vector_type(8))) short bf16x8;
typedef __attribute__((ext_vector_type(4))) float f32x4;

// d_ws layout: ushort view for bf16 frags, float view for biases
#define WS_WHH0_U 0         // 16384 ushort
#define WS_WIH1_U 16384
#define WS_WHH1_U 32768
#define WS_WIH0_U 49152     // 8192 ushort -> ends at byte 114688
#define WS_B0_F   28672     // float idx (byte 114688)
#define WS_B1_F   28928

#define MFMA(A,B,C) __builtin_amdgcn_mfma_f32_16x16x32_bf16(A,B,C,0,0,0)
#define LOG2E 1.4426950408889634f

// RNE (one-shot weight formatting only)
__device__ __forceinline__ unsigned short f2bf_rne(float f) {
    unsigned int u = __float_as_uint(f);
    u += 0x7fffu + ((u >> 16) & 1u);
    return (unsigned short)(u >> 16);
}
// hot-loop: round-nearest-ties-up, 2 VALU ops
__device__ __forceinline__ unsigned short f2bf(float f) {
    return (unsigned short)((__float_as_uint(f) + 0x8000u) >> 16);
}
// y already equals -L*(x+b):  sigmoid = 1/(1+2^y)
__device__ __forceinline__ float sig_from_y(float y) {
    return __builtin_amdgcn_rcpf(1.0f + __builtin_amdgcn_exp2f(y));
}
// y already equals 2L*(x+b):  tanh = 1 - 2/(2^y+1)
__device__ __forceinline__ float tanh_from_y(float y) {
    const float e = __builtin_amdgcn_exp2f(y);
    return fmaf(-2.0f, __builtin_amdgcn_rcpf(e + 1.0f), 1.0f);
}
__device__ __forceinline__ float ftanh(float x) {
    return tanh_from_y((2.0f * LOG2E) * x);
}
// lgkm-only barrier: keeps the x global prefetch (vmcnt) in flight across
// the sync. __syncthreads() would drain vmcnt(0) and serialize HBM latency
// into every step.
__device__ __forceinline__ void bar_lds() {
    asm volatile("s_waitcnt lgkmcnt(0)\n\ts_barrier" ::: "memory");
}

// One-shot: format weights into per-lane MFMA B-fragment order (bf16) + fused biases.
// Frag (ug,G,kc): lane l, elem j  <->  W[row = G*64 + ug*16 + (l&15)][k = kc*32 + (l>>4)*8 + j]
__global__ void reorder_w(const float* __restrict__ Wih0, const float* __restrict__ Whh0,
                          const float* __restrict__ bih0, const float* __restrict__ bhh0,
                          const float* __restrict__ Wih1, const float* __restrict__ Whh1,
                          const float* __restrict__ bih1, const float* __restrict__ bhh1,
                          unsigned short* __restrict__ wsu, float* __restrict__ wsf)
{
    const int idx = blockIdx.x * 256 + threadIdx.x;   // 0..24575
    if (idx < 16384) {
        const int j = idx & 7, lane = (idx >> 3) & 63, kc = (idx >> 9) & 1,
                  G = (idx >> 10) & 3, ug = (idx >> 12) & 3;
        const int row = G * 64 + ug * 16 + (lane & 15);
        const int k   = kc * 32 + (lane >> 4) * 8 + j;
        wsu[WS_WHH0_U + idx] = f2bf_rne(Whh0[row * 64 + k]);
        wsu[WS_WIH1_U + idx] = f2bf_rne(Wih1[row * 64 + k]);
        wsu[WS_WHH1_U + idx] = f2bf_rne(Whh1[row * 64 + k]);
    }
    if (idx < 8192) {
        const int j = idx & 7, lane = (idx >> 3) & 63, G = (idx >> 9) & 3, ug = (idx >> 11) & 3;
        const int row = G * 64 + ug * 16 + (lane & 15);
        const float v = ((lane >> 4) == 0 && j < 4) ? Wih0[row * 4 + j] : 0.0f;
        wsu[WS_WIH0_U + idx] = f2bf_rne(v);
    }
    if (idx < 256) {
        wsf[WS_B0_F + idx] = bih0[idx] + bhh0[idx];
        wsf[WS_B1_F + idx] = bih1[idx] + bhh1[idx];
    }
}

// 4-wave blocks: 2 independent blocks/CU (vs 1x 8-wave block) so one block's
// barrier bubbles are filled by the other. (256,2): VGPR cap 256, weights
// stay register/AGPR-resident (round-5 lesson: cap 128 -> 4GB scratch spill).
__global__ __launch_bounds__(256, 2) void lstm2_mfma(
    const float* __restrict__ x,
    const unsigned short* __restrict__ wsu, const float* __restrict__ wsf,
    const float* __restrict__ gam, const float* __restrict__ bet,
    const float* __restrict__ Wfc, const float* __restrict__ bfc,
    float* __restrict__ out)
{
    // Fragment-native h store: element (m=batch, k=unit) at byte
    //   kc*1024 + ((k>>3)&3)*256 + m*16 + (k&7)*2   (kc = k>>5)
    // => A-frag read for lane l is bytes [l*16, l*16+16) (+1024 for kc=1):
    //    perfectly sequential across the wave, ZERO bank conflicts.
    __shared__ __align__(16) unsigned short H0[1024];   // 2 KB
    __shared__ __align__(16) unsigned short H1[1024];
    __shared__ float H1F[BC * 65];   // f32 h1 for LN epilogue (last step only)

    const int tid  = threadIdx.x;
    const int lane = tid & 63;
    const int ug   = __builtin_amdgcn_readfirstlane(tid >> 6); // 0..3 unit-group
    const int ln15 = lane & 15, lg = lane >> 4;
    const int bblk = blockIdx.x * BC;

    // ---- resident weight B-fragments (one-time) ----
    bf16x8 Bhh0[4][2], Bih1[4][2], Bhh1[4][2], Bih0[4];
    #pragma unroll
    for (int G = 0; G < 4; ++G) {
        #pragma unroll
        for (int kc = 0; kc < 2; ++kc) {
            const int f = ((ug * 4 + G) * 2 + kc) * 512 + lane * 8;
            Bhh0[G][kc] = *(const bf16x8*)(wsu + WS_WHH0_U + f);
            Bih1[G][kc] = *(const bf16x8*)(wsu + WS_WIH1_U + f);
            Bhh1[G][kc] = *(const bf16x8*)(wsu + WS_WHH1_U + f);
        }
        Bih0[G] = *(const bf16x8*)(wsu + WS_WIH0_U + (ug * 4 + G) * 512 + lane * 8);
    }
    // biases folded into activation constants: sigmoid uses y=-L*(x+b),
    // tanh uses y=2L*(x+b); premultiply so the gate's first MUL becomes FMA.
    float lb0[4], lb1[4];
    #pragma unroll
    for (int G = 0; G < 4; ++G) {
        const float b0 = wsf[WS_B0_F + G * 64 + ug * 16 + ln15];
        const float b1 = wsf[WS_B1_F + G * 64 + ug * 16 + ln15];
        lb0[G] = (G == 2) ? (2.0f * LOG2E) * b0 : -LOG2E * b0;
        lb1[G] = (G == 2) ? (2.0f * LOG2E) * b1 : -LOG2E * b1;
    }
    const f32x4 zero4 = {0.f, 0.f, 0.f, 0.f};

    // ---- t-invariant LDS byte addresses ----
    const int kcw = ug >> 1;
    const int lgc = ((ug & 1) << 1) + (ln15 >> 3);
    const unsigned wbase = (unsigned)(kcw * 1024 + lgc * 256 + lg * 64 + (ln15 & 7) * 2);
    const unsigned rbase = (unsigned)(lane * 16);
    char* const H0c = (char*)H0;
    char* const H1c = (char*)H1;

    float c0[4] = {0.f,0.f,0.f,0.f}, c1[4] = {0.f,0.f,0.f,0.f};
    const bf16x8 zfrag = {0,0,0,0,0,0,0,0};
    bf16x8 A0[2], A1[2];
    A0[0] = zfrag; A0[1] = zfrag; A1[0] = zfrag; A1[1] = zfrag;   // h(-1) = 0

    const float* xb = x + (size_t)(bblk + ln15) * (TSTEPS * 4);
    float4 xf = *(const float4*)(xb);   // x_0

    for (int t = 0; t < TSTEPS; ++t) {
        // ---------- layer 0 ----------
        bf16x8 ax = zfrag;
        if (lg == 0) {
            ax[0] = (short)f2bf_rne(xf.x); ax[1] = (short)f2bf_rne(xf.y);
            ax[2] = (short)f2bf_rne(xf.z); ax[3] = (short)f2bf_rne(xf.w);
        }
        f32x4 acc[4];
        #pragma unroll
        for (int G = 0; G < 4; ++G) {
            acc[G] = MFMA(A0[0], Bhh0[G][0], zero4);
            acc[G] = MFMA(A0[1], Bhh0[G][1], acc[G]);
            acc[G] = MFMA(ax,    Bih0[G],    acc[G]);
        }
        if (t + 1 < TSTEPS) xf = *(const float4*)(xb + (t + 1) * 4);  // prefetch

        #pragma unroll
        for (int r = 0; r < 4; ++r) {
            const float ig = sig_from_y(fmaf(-LOG2E, acc[0][r], lb0[0]));
            const float fg = sig_from_y(fmaf(-LOG2E, acc[1][r], lb0[1]));
            const float gg = tanh_from_y(fmaf(2.0f * LOG2E, acc[2][r], lb0[2]));
            const float og = sig_from_y(fmaf(-LOG2E, acc[3][r], lb0[3]));
            const float c = fg * c0[r] + ig * gg; c0[r] = c;
            *(unsigned short*)(H0c + wbase + r * 16) = f2bf(og * ftanh(c));
        }
        bar_lds();   // publish h0
        A0[0] = *(const bf16x8*)(H0c + rbase);
        A0[1] = *(const bf16x8*)(H0c + rbase + 1024);

        // ---------- layer 1 ----------
        #pragma unroll
        for (int G = 0; G < 4; ++G) {
            acc[G] = MFMA(A0[0], Bih1[G][0], zero4);
            acc[G] = MFMA(A0[1], Bih1[G][1], acc[G]);
            acc[G] = MFMA(A1[0], Bhh1[G][0], acc[G]);
            acc[G] = MFMA(A1[1], Bhh1[G][1], acc[G]);
        }
        #pragma unroll
        for (int r = 0; r < 4; ++r) {
            const float ig = sig_from_y(fmaf(-LOG2E, acc[0][r], lb1[0]));
            const float fg = sig_from_y(fmaf(-LOG2E, acc[1][r], lb1[1]));
            const float gg = tanh_from_y(fmaf(2.0f * LOG2E, acc[2][r], lb1[2]));
            const float og = sig_from_y(fmaf(-LOG2E, acc[3][r], lb1[3]));
            const float c = fg * c1[r] + ig * gg; c1[r] = c;
            const float h = og * ftanh(c);
            *(unsigned short*)(H1c + wbase + r * 16) = f2bf(h);
            if (t == TSTEPS - 1)
                H1F[(lg * 4 + r) * 65 + ug * 16 + ln15] = h;
        }
        bar_lds();   // publish h1
        A1[0] = *(const bf16x8*)(H1c + rbase);
        A1[1] = *(const bf16x8*)(H1c + rbase + 1024);
    }

    // ---------- LayerNorm + FC on h1(T-1), f32 path ----------
    if (tid < BC) {
        const int b = tid;
        float hr[64];
        float mu = 0.f;
        #pragma unroll
        for (int k = 0; k < 64; ++k) { hr[k] = H1F[b * 65 + k]; mu += hr[k]; }
        mu *= (1.f / 64.f);
        float var = 0.f;
        #pragma unroll
        for (int k = 0; k < 64; ++k) { const float d = hr[k] - mu; var = fmaf(d, d, var); }
        var *= (1.f / 64.f);
        const float rs = rsqrtf(var + 1e-5f);
        float o0 = bfc[0], o1 = bfc[1];
        #pragma unroll
        for (int k = 0; k < 64; ++k) {
            const float nk = (hr[k] - mu) * rs * gam[k] + bet[k];
            o0 = fmaf(nk, Wfc[k],      o0);
            o1 = fmaf(nk, Wfc[64 + k], o1);
        }
        out[(size_t)(bblk + b) * 2 + 0] = o0;
        out[(size_t)(bblk + b) * 2 + 1] = o1;
    }
}

extern "C" void kernel_launch(void* const* d_in, const int* in_sizes, int n_in,
                              void* d_out, int out_size, void* d_ws, size_t ws_size,
                              hipStream_t stream) {
    (void)in_sizes; (void)n_in; (void)out_size; (void)ws_size;
    const float* x    = (const float*)d_in[0];
    const float* Wih0 = (const float*)d_in[1];
    const float* Whh0 = (const float*)d_in[2];
    const float* bih0 = (const float*)d_in[3];
    const float* bhh0 = (const float*)d_in[4];
    const float* Wih1 = (const float*)d_in[5];
    const float* Whh1 = (const float*)d_in[6];
    const float* bih1 = (const float*)d_in[7];
    const float* bhh1 = (const float*)d_in[8];
    const float* gam  = (const float*)d_in[9];
    const float* bet  = (const float*)d_in[10];
    const float* Wfc  = (const float*)d_in[11];
    const float* bfc  = (const float*)d_in[12];
    unsigned short* wsu = (unsigned short*)d_ws;
    float*          wsf = (float*)d_ws;
    float* out = (float*)d_out;

    hipLaunchKernelGGL(reorder_w, dim3(96), dim3(256), 0, stream,
                       Wih0, Whh0, bih0, bhh0, Wih1, Whh1, bih1, bhh1, wsu, wsf);
    hipLaunchKernelGGL(lstm2_mfma, dim3(NBLK), dim3(256), 0, stream,
                       x, wsu, wsf, gam, bet, Wfc, bfc, out);
}